// Round 7
// baseline (256.983 us; speedup 1.0000x reference)
//
#include <hip/hip_runtime.h>
#include <math.h>

#define TAU_F 32.0f

typedef __attribute__((ext_vector_type(8))) _Float16 half8;
typedef __attribute__((ext_vector_type(2))) __fp16 half2v;
typedef __attribute__((ext_vector_type(4))) float f32x4;

union HU { uint4 u; half8 v; };

// ============ Kernel 1: G partials, fp32 VALU, no atomics (unchanged) ============
// P[ks][192][2048], ks=4. Rows: 0..89 topic, 90..95 zero, 96..185 domain, 186..191 zero.
__global__ __launch_bounds__(256) void gproj2(
    const float* __restrict__ Wt, const float* __restrict__ Wd,
    const float* __restrict__ mem, const int* __restrict__ cat,
    float* __restrict__ P)
{
    __shared__ float Ml[96 * 36];
    __shared__ float Wl[32 * 68];

    const int bid = blockIdx.x;
    const int mat = bid >> 7;
    const int ks  = (bid >> 5) & 3;
    const int ct  = bid & 31;
    const int c0  = ct * 64;
    const int tid = threadIdx.x;
    const float* __restrict__ W = mat ? Wd : Wt;

    const int tr = tid >> 4;
    const int tc = tid & 15;

    float acc[6][4];
    #pragma unroll
    for (int j = 0; j < 6; ++j)
        #pragma unroll
        for (int q = 0; q < 4; ++q) acc[j][q] = 0.f;

    for (int ch = 0; ch < 6; ++ch) {
        __syncthreads();
        #pragma unroll
        for (int p = 0; p < 3; ++p) {
            const int idx = tid + 256 * p;
            const int r   = idx >> 3;
            const int kq  = idx & 7;
            float4 v = make_float4(0.f, 0.f, 0.f, 0.f);
            if (r < 90) {
                const int d = r / 10;
                const int mrow = cat[d] * 10 + (r - d * 10);
                v = *(const float4*)(mem + (size_t)mrow * 768 + ks * 192 + ch * 32 + kq * 4);
            }
            *(float4*)(Ml + r * 36 + kq * 4) = v;
        }
        #pragma unroll
        for (int p = 0; p < 2; ++p) {
            const int idx = tid + 256 * p;
            const int e   = idx >> 4;
            const int c4  = (idx & 15) * 4;
            *(float4*)(Wl + e * 68 + c4) =
                *(const float4*)(W + (size_t)(ks * 192 + ch * 32 + e) * 2048 + c0 + c4);
        }
        __syncthreads();

        #pragma unroll
        for (int e = 0; e < 32; e += 4) {
            float4 m4[6], w4[4];
            #pragma unroll
            for (int j = 0; j < 6; ++j) m4[j] = *(const float4*)(Ml + (tr * 6 + j) * 36 + e);
            #pragma unroll
            for (int q = 0; q < 4; ++q) w4[q] = *(const float4*)(Wl + (e + q) * 68 + tc * 4);
            #pragma unroll
            for (int j = 0; j < 6; ++j) {
                const float mv[4] = {m4[j].x, m4[j].y, m4[j].z, m4[j].w};
                #pragma unroll
                for (int q = 0; q < 4; ++q) {
                    acc[j][0] = fmaf(mv[q], w4[q].x, acc[j][0]);
                    acc[j][1] = fmaf(mv[q], w4[q].y, acc[j][1]);
                    acc[j][2] = fmaf(mv[q], w4[q].z, acc[j][2]);
                    acc[j][3] = fmaf(mv[q], w4[q].w, acc[j][3]);
                }
            }
        }
    }

    #pragma unroll
    for (int j = 0; j < 6; ++j) {
        float4 v = make_float4(acc[j][0], acc[j][1], acc[j][2], acc[j][3]);
        *(float4*)(P + (size_t)ks * 393216 + (size_t)(mat * 96 + tr * 6 + j) * 2048 + c0 + tc * 4) = v;
    }
}

// ============ Kernel 2: reduce partials -> f16 hi/lo, fragment-major (unchanged) ============
// frag f = (kcg*12 + nq*3 + j)*2 + plane; addr = f*512 + lq*128 + lm*8
__global__ __launch_bounds__(256) void split_g3(
    const float* __restrict__ P, unsigned short* __restrict__ gB)
{
    const int u  = blockIdx.x * 256 + threadIdx.x;  // 0..49151
    const int n  = u >> 8;                          // 0..191
    const int k0 = (u & 255) * 8;                   // 0..2040

    float s[8] = {0.f, 0.f, 0.f, 0.f, 0.f, 0.f, 0.f, 0.f};
    #pragma unroll
    for (int ks = 0; ks < 4; ++ks) {
        const float4 a = *(const float4*)(P + (size_t)ks * 393216 + (size_t)n * 2048 + k0);
        const float4 b = *(const float4*)(P + (size_t)ks * 393216 + (size_t)n * 2048 + k0 + 4);
        s[0] += a.x; s[1] += a.y; s[2] += a.z; s[3] += a.w;
        s[4] += b.x; s[5] += b.y; s[6] += b.z; s[7] += b.w;
    }
    union { _Float16 h[8]; uint4 u4; } hi, lo;
    #pragma unroll
    for (int e = 0; e < 8; ++e) {
        const _Float16 h = (_Float16)s[e];
        hi.h[e] = h;
        lo.h[e] = (_Float16)(s[e] - (float)h);
    }
    const int kc = k0 >> 5;
    const int lq = (k0 >> 3) & 3;
    const int nq = n / 48;
    const int rm = n - nq * 48;
    const int j  = rm >> 4;
    const int lm = rm & 15;
    const size_t fH = (size_t)((kc * 12 + nq * 3 + j) * 2 + 0) * 512 + lq * 128 + lm * 8;
    const size_t fL = (size_t)((kc * 12 + nq * 3 + j) * 2 + 1) * 512 + lq * 128 + lm * 8;
    *(uint4*)(gB + fH) = hi.u4;
    *(uint4*)(gB + fL) = lo.u4;
}

// ============ Kernel 3: M=64 x K-split-2 split-f16 MFMA, 3 blocks/CU occupancy ============
// 512 blocks (rt=bid>>1 row-tile of 64, ks=bid&1 K-slice of 1024), 256 thr = 4 waves (nq).
__global__ __launch_bounds__(256, 3) void fused_mfma5(
    const float* __restrict__ feat, const unsigned short* __restrict__ gB,
    float* __restrict__ P2, float* __restrict__ ssqp)
{
    __shared__ __align__(16) unsigned short aS[10240];  // [buf2][plane2][row64][40] = 20 KB

    const int tid = threadIdx.x;
    const int rt  = blockIdx.x >> 1;
    const int ks  = blockIdx.x & 1;
    const int row0 = rt * 64;

    const int nq = tid >> 6, l = tid & 63;
    const int lm = l & 15,  lq = l >> 4;
    const int r8 = tid >> 2, kq = tid & 3;   // staging: row 0..63, k-octet 0..3

    f32x4 acc[4][3];
    #pragma unroll
    for (int i = 0; i < 4; ++i)
        #pragma unroll
        for (int j = 0; j < 3; ++j) acc[i][j] = (f32x4)0.f;
    float ssq = 0.f;

    const float* fbase = feat + (size_t)(row0 + r8) * 2048 + ks * 1024 + kq * 8;
    const unsigned short* bbase = gB + (size_t)ks * 393216 + (nq * 3) * 1024 + l * 8;

    // ---- prologue ----
    float4 f0 = *(const float4*)(fbase);
    float4 f1 = *(const float4*)(fbase + 4);
    uint4 bh[3], bl[3];
    #pragma unroll
    for (int j = 0; j < 3; ++j) {
        bh[j] = *(const uint4*)(bbase + j * 1024);
        bl[j] = *(const uint4*)(bbase + j * 1024 + 512);
    }
    // convert chunk 0 -> buf 0
    {
        const float xs[8] = {f0.x, f0.y, f0.z, f0.w, f1.x, f1.y, f1.z, f1.w};
        union { half2v h2[4]; uint4 u4; } uh, ul;
        #pragma unroll
        for (int e = 0; e < 4; ++e) {
            const float a = xs[2 * e], b = xs[2 * e + 1];
            ssq = fmaf(a, a, ssq); ssq = fmaf(b, b, ssq);
            half2v h = __builtin_amdgcn_cvt_pkrtz(a, b);
            uh.h2[e] = h;
            ul.h2[e] = __builtin_amdgcn_cvt_pkrtz(a - (float)h[0], b - (float)h[1]);
        }
        *(uint4*)(aS + 0 * 2560 + r8 * 40 + kq * 8) = uh.u4;
        *(uint4*)(aS + 1 * 2560 + r8 * 40 + kq * 8) = ul.u4;
    }
    // A prefetch chunk 1
    float4 fn0 = *(const float4*)(fbase + 32);
    float4 fn1 = *(const float4*)(fbase + 36);
    __syncthreads();

    for (int kc = 0; kc < 32; ++kc) {
        // issue A load for chunk kc+2 (used 2 iters later)
        const int ka = (kc + 2 < 32) ? kc + 2 : 31;
        float4 fa0 = *(const float4*)(fbase + ka * 32);
        float4 fa1 = *(const float4*)(fbase + ka * 32 + 4);
        // issue B loads for chunk kc+1 (used next iter)
        const int kb = (kc + 1 < 32) ? kc + 1 : 31;
        uint4 bhn[3], bln[3];
        #pragma unroll
        for (int j = 0; j < 3; ++j) {
            bhn[j] = *(const uint4*)(bbase + (size_t)kb * 12288 + j * 1024);
            bln[j] = *(const uint4*)(bbase + (size_t)kb * 12288 + j * 1024 + 512);
        }

        // convert chunk kc+1 -> buf (kc+1)&1
        if (kc < 31) {
            const int nb = (kc + 1) & 1;
            const float xs[8] = {fn0.x, fn0.y, fn0.z, fn0.w, fn1.x, fn1.y, fn1.z, fn1.w};
            union { half2v h2[4]; uint4 u4; } uh, ul;
            #pragma unroll
            for (int e = 0; e < 4; ++e) {
                const float a = xs[2 * e], b = xs[2 * e + 1];
                ssq = fmaf(a, a, ssq); ssq = fmaf(b, b, ssq);
                half2v h = __builtin_amdgcn_cvt_pkrtz(a, b);
                uh.h2[e] = h;
                ul.h2[e] = __builtin_amdgcn_cvt_pkrtz(a - (float)h[0], b - (float)h[1]);
            }
            *(uint4*)(aS + (nb * 2 + 0) * 2560 + r8 * 40 + kq * 8) = uh.u4;
            *(uint4*)(aS + (nb * 2 + 1) * 2560 + r8 * 40 + kq * 8) = ul.u4;
        }

        // MFMA on buf kc&1
        const int cb = kc & 1;
        const unsigned short* aH = aS + (cb * 2 + 0) * 2560;
        const unsigned short* aL = aS + (cb * 2 + 1) * 2560;
        half8 fh[4], fl[4];
        #pragma unroll
        for (int i = 0; i < 4; ++i) {
            HU th, tl;
            th.u = *(const uint4*)(aH + (i * 16 + lm) * 40 + lq * 8);
            tl.u = *(const uint4*)(aL + (i * 16 + lm) * 40 + lq * 8);
            fh[i] = th.v; fl[i] = tl.v;
        }
        #pragma unroll
        for (int j = 0; j < 3; ++j) {
            HU h8, l8; h8.u = bh[j]; l8.u = bl[j];
            #pragma unroll
            for (int i = 0; i < 4; ++i) {
                acc[i][j] = __builtin_amdgcn_mfma_f32_16x16x32_f16(fh[i], h8.v, acc[i][j], 0, 0, 0);
                acc[i][j] = __builtin_amdgcn_mfma_f32_16x16x32_f16(fh[i], l8.v, acc[i][j], 0, 0, 0);
                acc[i][j] = __builtin_amdgcn_mfma_f32_16x16x32_f16(fl[i], h8.v, acc[i][j], 0, 0, 0);
            }
        }
        __syncthreads();

        // rotate prefetch regs
        fn0 = fa0; fn1 = fa1;
        #pragma unroll
        for (int j = 0; j < 3; ++j) { bh[j] = bhn[j]; bl[j] = bln[j]; }
    }

    // ssq: 4 staging threads per row (lanes l, l^1, l^2 same row)
    ssq += __shfl_xor(ssq, 1, 64);
    ssq += __shfl_xor(ssq, 2, 64);
    if ((tid & 3) == 0) ssqp[(size_t)ks * 16384 + row0 + (tid >> 2)] = ssq;

    // partial scores out (D layout: row = lq*4+r, col = lm)
    #pragma unroll
    for (int i = 0; i < 4; ++i)
        #pragma unroll
        for (int j = 0; j < 3; ++j)
            #pragma unroll
            for (int r = 0; r < 4; ++r)
                P2[((size_t)ks * 16384 + row0 + i * 16 + lq * 4 + r) * 192 + nq * 48 + j * 16 + lm]
                    = acc[i][j][r];
}

// ============ Kernel 4: reduce K-split partials + softmax epilogue ============
#define EP_SPAD 196
__global__ __launch_bounds__(256) void ep_kernel(
    const float* __restrict__ P2, const float* __restrict__ ssqp,
    float* __restrict__ out)
{
    __shared__ float sc[64 * EP_SPAD];
    const int tid  = threadIdx.x;
    const int row0 = blockIdx.x * 64;

    float4 s[12];
    #pragma unroll
    for (int p = 0; p < 12; ++p) s[p] = make_float4(0.f, 0.f, 0.f, 0.f);
    #pragma unroll
    for (int ks = 0; ks < 2; ++ks)
        #pragma unroll
        for (int p = 0; p < 12; ++p) {
            const int u   = p * 256 + tid;
            const int row = u / 48;
            const int c4  = (u - row * 48) * 4;
            const float4 v = *(const float4*)(P2 + ((size_t)ks * 16384 + row0 + row) * 192 + c4);
            s[p].x += v.x; s[p].y += v.y; s[p].z += v.z; s[p].w += v.w;
        }
    #pragma unroll
    for (int p = 0; p < 12; ++p) {
        const int u   = p * 256 + tid;
        const int row = u / 48;
        const int c4  = (u - row * 48) * 4;
        *(float4*)(sc + row * EP_SPAD + c4) = s[p];
    }
    float nsq = 0.f;
    if (tid < 64) {
        nsq = ssqp[row0 + tid] + ssqp[16384 + row0 + tid];
    }
    __syncthreads();

    if (tid < 64) {
        const int r = tid;
        const float inv = TAU_F / fmaxf(sqrtf(nsq), 1e-12f);
        const float* scr = sc + (size_t)r * EP_SPAD;
        float lg[9];
        float dmax = -1e30f;
        #pragma unroll
        for (int d = 0; d < 9; ++d) {
            const float* v = scr + d * 10;          // topic rows 0..89
            const float* u = scr + 96 + d * 10;     // domain rows 96..185
            float mx = v[0];
            #pragma unroll
            for (int m = 1; m < 10; ++m) mx = fmaxf(mx, v[m]);
            float ssum = 0.f, dot = 0.f;
            #pragma unroll
            for (int m = 0; m < 10; ++m) {
                const float p = __expf((v[m] - mx) * inv);
                ssum += p;
                dot = fmaf(p, u[m], dot);
            }
            const float lgt = (dot / ssum) * inv;
            lg[d] = lgt;
            dmax = fmaxf(dmax, lgt);
        }
        float s2 = 0.f;
        #pragma unroll
        for (int d = 0; d < 9; ++d) { const float p = __expf(lg[d] - dmax); lg[d] = p; s2 += p; }
        const float r2 = 1.0f / s2;
        #pragma unroll
        for (int d = 0; d < 9; ++d)
            out[(size_t)(row0 + r) * 9 + d] = lg[d] * r2;
    }
}

extern "C" void kernel_launch(void* const* d_in, const int* in_sizes, int n_in,
                              void* d_out, int out_size, void* d_ws, size_t ws_size,
                              hipStream_t stream) {
    const float* feature = (const float*)d_in[0];
    const float* Wt      = (const float*)d_in[1];
    const float* Wd      = (const float*)d_in[2];
    const float* mem     = (const float*)d_in[3];
    const int*   cat     = (const int*)d_in[4];

    // ws layout: P2 (25.2 MB, aliases P's 6.3 MB — safe: P dead before fused writes P2,
    // stream-ordered) | gB 1.57 MB @50331648 | ssqp 128 KB
    float* P2 = (float*)d_ws;
    float* P  = (float*)d_ws;
    unsigned short* gB = (unsigned short*)((char*)d_ws + 50331648);
    float* ssqp = (float*)((char*)d_ws + 50331648 + 1572864);
    float* out = (float*)d_out;

    gproj2<<<256, 256, 0, stream>>>(Wt, Wd, mem, cat, P);
    split_g3<<<192, 256, 0, stream>>>(P, gB);
    fused_mfma5<<<512, 256, 0, stream>>>(feature, gB, P2, ssqp);
    ep_kernel<<<256, 256, 0, stream>>>(P2, ssqp, out);
}

// Round 8
// 250.078 us; speedup vs baseline: 1.0276x; 1.0276x over previous
//
#include <hip/hip_runtime.h>
#include <math.h>

#define TAU_F 32.0f

typedef __attribute__((ext_vector_type(8))) _Float16 half8;
typedef __attribute__((ext_vector_type(2))) __fp16 half2v;
typedef __attribute__((ext_vector_type(4))) float f32x4;

union HU { uint4 u; half8 v; };

__device__ __forceinline__ void sync_lds_only() {
    // CK-style block_sync_lds: drain LDS ops, leave VMEM (vmcnt) in flight.
    asm volatile("s_waitcnt lgkmcnt(0)" ::: "memory");
    __builtin_amdgcn_s_barrier();
}

// ============ Kernel 1: G partials, fp32 VALU, no atomics (unchanged) ============
// P[ks][192][2048], ks=4. Rows: 0..89 topic, 90..95 zero, 96..185 domain, 186..191 zero.
__global__ __launch_bounds__(256) void gproj2(
    const float* __restrict__ Wt, const float* __restrict__ Wd,
    const float* __restrict__ mem, const int* __restrict__ cat,
    float* __restrict__ P)
{
    __shared__ float Ml[96 * 36];
    __shared__ float Wl[32 * 68];

    const int bid = blockIdx.x;
    const int mat = bid >> 7;
    const int ks  = (bid >> 5) & 3;
    const int ct  = bid & 31;
    const int c0  = ct * 64;
    const int tid = threadIdx.x;
    const float* __restrict__ W = mat ? Wd : Wt;

    const int tr = tid >> 4;
    const int tc = tid & 15;

    float acc[6][4];
    #pragma unroll
    for (int j = 0; j < 6; ++j)
        #pragma unroll
        for (int q = 0; q < 4; ++q) acc[j][q] = 0.f;

    for (int ch = 0; ch < 6; ++ch) {
        __syncthreads();
        #pragma unroll
        for (int p = 0; p < 3; ++p) {
            const int idx = tid + 256 * p;
            const int r   = idx >> 3;
            const int kq  = idx & 7;
            float4 v = make_float4(0.f, 0.f, 0.f, 0.f);
            if (r < 90) {
                const int d = r / 10;
                const int mrow = cat[d] * 10 + (r - d * 10);
                v = *(const float4*)(mem + (size_t)mrow * 768 + ks * 192 + ch * 32 + kq * 4);
            }
            *(float4*)(Ml + r * 36 + kq * 4) = v;
        }
        #pragma unroll
        for (int p = 0; p < 2; ++p) {
            const int idx = tid + 256 * p;
            const int e   = idx >> 4;
            const int c4  = (idx & 15) * 4;
            *(float4*)(Wl + e * 68 + c4) =
                *(const float4*)(W + (size_t)(ks * 192 + ch * 32 + e) * 2048 + c0 + c4);
        }
        __syncthreads();

        #pragma unroll
        for (int e = 0; e < 32; e += 4) {
            float4 m4[6], w4[4];
            #pragma unroll
            for (int j = 0; j < 6; ++j) m4[j] = *(const float4*)(Ml + (tr * 6 + j) * 36 + e);
            #pragma unroll
            for (int q = 0; q < 4; ++q) w4[q] = *(const float4*)(Wl + (e + q) * 68 + tc * 4);
            #pragma unroll
            for (int j = 0; j < 6; ++j) {
                const float mv[4] = {m4[j].x, m4[j].y, m4[j].z, m4[j].w};
                #pragma unroll
                for (int q = 0; q < 4; ++q) {
                    acc[j][0] = fmaf(mv[q], w4[q].x, acc[j][0]);
                    acc[j][1] = fmaf(mv[q], w4[q].y, acc[j][1]);
                    acc[j][2] = fmaf(mv[q], w4[q].z, acc[j][2]);
                    acc[j][3] = fmaf(mv[q], w4[q].w, acc[j][3]);
                }
            }
        }
    }

    #pragma unroll
    for (int j = 0; j < 6; ++j) {
        float4 v = make_float4(acc[j][0], acc[j][1], acc[j][2], acc[j][3]);
        *(float4*)(P + (size_t)ks * 393216 + (size_t)(mat * 96 + tr * 6 + j) * 2048 + c0 + tc * 4) = v;
    }
}

// ============ Kernel 2: reduce partials -> f16 hi/lo, fragment-major (unchanged) ============
// frag f = (kcg*12 + nq*3 + j)*2 + plane; addr = f*512 + lq*128 + lm*8
__global__ __launch_bounds__(256) void split_g3(
    const float* __restrict__ P, unsigned short* __restrict__ gB)
{
    const int u  = blockIdx.x * 256 + threadIdx.x;  // 0..49151
    const int n  = u >> 8;                          // 0..191
    const int k0 = (u & 255) * 8;                   // 0..2040

    float s[8] = {0.f, 0.f, 0.f, 0.f, 0.f, 0.f, 0.f, 0.f};
    #pragma unroll
    for (int ks = 0; ks < 4; ++ks) {
        const float4 a = *(const float4*)(P + (size_t)ks * 393216 + (size_t)n * 2048 + k0);
        const float4 b = *(const float4*)(P + (size_t)ks * 393216 + (size_t)n * 2048 + k0 + 4);
        s[0] += a.x; s[1] += a.y; s[2] += a.z; s[3] += a.w;
        s[4] += b.x; s[5] += b.y; s[6] += b.z; s[7] += b.w;
    }
    union { _Float16 h[8]; uint4 u4; } hi, lo;
    #pragma unroll
    for (int e = 0; e < 8; ++e) {
        const _Float16 h = (_Float16)s[e];   // RNE
        hi.h[e] = h;
        lo.h[e] = (_Float16)(s[e] - (float)h);
    }
    const int kc = k0 >> 5;
    const int lq = (k0 >> 3) & 3;
    const int nq = n / 48;
    const int rm = n - nq * 48;
    const int j  = rm >> 4;
    const int lm = rm & 15;
    const size_t fH = (size_t)((kc * 12 + nq * 3 + j) * 2 + 0) * 512 + lq * 128 + lm * 8;
    const size_t fL = (size_t)((kc * 12 + nq * 3 + j) * 2 + 1) * 512 + lq * 128 + lm * 8;
    *(uint4*)(gB + fH) = hi.u4;
    *(uint4*)(gB + fL) = lo.u4;
}

// ============ Kernel 3: raw-barrier split-f16 MFMA, wave-specialized passes ============
// 512 blocks (rt=bid>>1 row-tile of 64, ks=bid&1 K-slice of 1024), 256 thr = 4 waves.
// Wave role nq=(w+bid)&3: nq<2 => topic cols (exact 3-pass), nq>=2 => domain cols (1-pass).
// Barriers are s_waitcnt lgkmcnt(0)+s_barrier only: global prefetch never drained.
__global__ __launch_bounds__(256, 2) void fused_mfma6(
    const float* __restrict__ feat, const unsigned short* __restrict__ gB,
    float* __restrict__ P2, float* __restrict__ ssqp)
{
    __shared__ __align__(16) unsigned short aS[4 * 64 * 44];  // [buf2][plane2][row64][44] = 22.5 KB

    const int tid = threadIdx.x;
    const int rt  = blockIdx.x >> 1;
    const int ks  = blockIdx.x & 1;
    const int row0 = rt * 64;

    const int w  = tid >> 6, l = tid & 63;
    const int lm = l & 15,  lq = l >> 4;
    const int nq = (w + blockIdx.x) & 3;     // role rotation balances SIMDs across blocks
    const bool topic = (nq < 2);
    const int r8 = tid >> 2, kq = tid & 3;   // staging: row 0..63, k-octet 0..3

    f32x4 acc[4][3];
    #pragma unroll
    for (int i = 0; i < 4; ++i)
        #pragma unroll
        for (int j = 0; j < 3; ++j) acc[i][j] = (f32x4)0.f;
    float ssq = 0.f;

    const float* fbase = feat + (size_t)(row0 + r8) * 2048 + ks * 1024 + kq * 8;
    const unsigned short* bbase = gB + (size_t)ks * 393216 + nq * 3072 + l * 8;

    // ---- prologue: A chunks 0,1 into regs; B chunk 0 into regs ----
    float4 c0a = *(const float4*)(fbase);
    float4 c0b = *(const float4*)(fbase + 4);
    float4 c1a = *(const float4*)(fbase + 32);
    float4 c1b = *(const float4*)(fbase + 36);
    uint4 bh[3], bl[3];
    #pragma unroll
    for (int j = 0; j < 3; ++j) bh[j] = *(const uint4*)(bbase + j * 1024);
    if (topic) {
        #pragma unroll
        for (int j = 0; j < 3; ++j) bl[j] = *(const uint4*)(bbase + j * 1024 + 512);
    }

    // convert+stage helper (fp32 -> f16 hi/lo planes, fused ssq)
    auto cw = [&](int buf, float4 va, float4 vb) {
        const float xs[8] = {va.x, va.y, va.z, va.w, vb.x, vb.y, vb.z, vb.w};
        union { half2v h2[4]; uint4 u4; } uh, ul;
        #pragma unroll
        for (int e = 0; e < 4; ++e) {
            const float a = xs[2 * e], b = xs[2 * e + 1];
            ssq = fmaf(a, a, ssq); ssq = fmaf(b, b, ssq);
            half2v h = __builtin_amdgcn_cvt_pkrtz(a, b);
            uh.h2[e] = h;
            ul.h2[e] = __builtin_amdgcn_cvt_pkrtz(a - (float)h[0], b - (float)h[1]);
        }
        *(uint4*)(aS + (size_t)((buf * 2 + 0) * 64 + r8) * 44 + kq * 8) = uh.u4;
        *(uint4*)(aS + (size_t)((buf * 2 + 1) * 64 + r8) * 44 + kq * 8) = ul.u4;
    };

    cw(0, c0a, c0b);
    sync_lds_only();

    for (int kc = 0; kc < 32; ++kc) {
        // B loads for kc+1 (ride through the barrier; never drained)
        const int kb = (kc + 1 < 32) ? kc + 1 : 31;
        uint4 bhn[3], bln[3];
        #pragma unroll
        for (int j = 0; j < 3; ++j)
            bhn[j] = *(const uint4*)(bbase + (size_t)kb * 12288 + j * 1024);
        if (topic) {
            #pragma unroll
            for (int j = 0; j < 3; ++j)
                bln[j] = *(const uint4*)(bbase + (size_t)kb * 12288 + j * 1024 + 512);
        }
        // A loads for kc+2
        const int ka = (kc + 2 < 32) ? kc + 2 : 31;
        float4 cna = *(const float4*)(fbase + ka * 32);
        float4 cnb = *(const float4*)(fbase + ka * 32 + 4);

        // convert chunk kc+1 -> buf (kc+1)&1 (other buffer; no race with this-iter reads)
        if (kc < 31) cw((kc + 1) & 1, c1a, c1b);

        // A fragments from buf kc&1
        const int cb = kc & 1;
        half8 fh[4], fl[4];
        #pragma unroll
        for (int i = 0; i < 4; ++i) {
            HU th;
            th.u = *(const uint4*)(aS + (size_t)((cb * 2 + 0) * 64 + i * 16 + lm) * 44 + lq * 8);
            fh[i] = th.v;
        }
        if (topic) {
            #pragma unroll
            for (int i = 0; i < 4; ++i) {
                HU tl;
                tl.u = *(const uint4*)(aS + (size_t)((cb * 2 + 1) * 64 + i * 16 + lm) * 44 + lq * 8);
                fl[i] = tl.v;
            }
        }

        if (topic) {
            #pragma unroll
            for (int j = 0; j < 3; ++j) {
                HU h8, l8; h8.u = bh[j]; l8.u = bl[j];
                #pragma unroll
                for (int i = 0; i < 4; ++i) {
                    acc[i][j] = __builtin_amdgcn_mfma_f32_16x16x32_f16(fh[i], h8.v, acc[i][j], 0, 0, 0);
                    acc[i][j] = __builtin_amdgcn_mfma_f32_16x16x32_f16(fh[i], l8.v, acc[i][j], 0, 0, 0);
                    acc[i][j] = __builtin_amdgcn_mfma_f32_16x16x32_f16(fl[i], h8.v, acc[i][j], 0, 0, 0);
                }
            }
        } else {
            #pragma unroll
            for (int j = 0; j < 3; ++j) {
                HU h8; h8.u = bh[j];
                #pragma unroll
                for (int i = 0; i < 4; ++i)
                    acc[i][j] = __builtin_amdgcn_mfma_f32_16x16x32_f16(fh[i], h8.v, acc[i][j], 0, 0, 0);
            }
        }

        sync_lds_only();   // lgkm drain + barrier only — vmcnt prefetch stays in flight

        c1a = cna; c1b = cnb;
        #pragma unroll
        for (int j = 0; j < 3; ++j) bh[j] = bhn[j];
        if (topic) {
            #pragma unroll
            for (int j = 0; j < 3; ++j) bl[j] = bln[j];
        }
    }

    // ssq: 4 staging threads per row (lanes l, l^1, l^2 cover kq 0..3 of same row)
    ssq += __shfl_xor(ssq, 1, 64);
    ssq += __shfl_xor(ssq, 2, 64);
    if (kq == 0) ssqp[(size_t)ks * 16384 + row0 + r8] = ssq;

    // partial scores out (D layout: row = lq*4+r, col = lm)
    #pragma unroll
    for (int i = 0; i < 4; ++i)
        #pragma unroll
        for (int j = 0; j < 3; ++j)
            #pragma unroll
            for (int r = 0; r < 4; ++r)
                P2[((size_t)ks * 16384 + row0 + i * 16 + lq * 4 + r) * 192 + nq * 48 + j * 16 + lm]
                    = acc[i][j][r];
}

// ============ Kernel 4: reduce K-split partials + softmax epilogue (unchanged) ============
#define EP_SPAD 196
__global__ __launch_bounds__(256) void ep_kernel(
    const float* __restrict__ P2, const float* __restrict__ ssqp,
    float* __restrict__ out)
{
    __shared__ float sc[64 * EP_SPAD];
    const int tid  = threadIdx.x;
    const int row0 = blockIdx.x * 64;

    float4 s[12];
    #pragma unroll
    for (int p = 0; p < 12; ++p) s[p] = make_float4(0.f, 0.f, 0.f, 0.f);
    #pragma unroll
    for (int ks = 0; ks < 2; ++ks)
        #pragma unroll
        for (int p = 0; p < 12; ++p) {
            const int u   = p * 256 + tid;
            const int row = u / 48;
            const int c4  = (u - row * 48) * 4;
            const float4 v = *(const float4*)(P2 + ((size_t)ks * 16384 + row0 + row) * 192 + c4);
            s[p].x += v.x; s[p].y += v.y; s[p].z += v.z; s[p].w += v.w;
        }
    #pragma unroll
    for (int p = 0; p < 12; ++p) {
        const int u   = p * 256 + tid;
        const int row = u / 48;
        const int c4  = (u - row * 48) * 4;
        *(float4*)(sc + row * EP_SPAD + c4) = s[p];
    }
    float nsq = 0.f;
    if (tid < 64) {
        nsq = ssqp[row0 + tid] + ssqp[16384 + row0 + tid];
    }
    __syncthreads();

    if (tid < 64) {
        const int r = tid;
        const float inv = TAU_F / fmaxf(sqrtf(nsq), 1e-12f);
        const float* scr = sc + (size_t)r * EP_SPAD;
        float lg[9];
        float dmax = -1e30f;
        #pragma unroll
        for (int d = 0; d < 9; ++d) {
            const float* v = scr + d * 10;          // topic rows 0..89
            const float* u = scr + 96 + d * 10;     // domain rows 96..185
            float mx = v[0];
            #pragma unroll
            for (int m = 1; m < 10; ++m) mx = fmaxf(mx, v[m]);
            float ssum = 0.f, dot = 0.f;
            #pragma unroll
            for (int m = 0; m < 10; ++m) {
                const float p = __expf((v[m] - mx) * inv);
                ssum += p;
                dot = fmaf(p, u[m], dot);
            }
            const float lgt = (dot / ssum) * inv;
            lg[d] = lgt;
            dmax = fmaxf(dmax, lgt);
        }
        float s2 = 0.f;
        #pragma unroll
        for (int d = 0; d < 9; ++d) { const float p = __expf(lg[d] - dmax); lg[d] = p; s2 += p; }
        const float r2 = 1.0f / s2;
        #pragma unroll
        for (int d = 0; d < 9; ++d)
            out[(size_t)(row0 + r) * 9 + d] = lg[d] * r2;
    }
}

extern "C" void kernel_launch(void* const* d_in, const int* in_sizes, int n_in,
                              void* d_out, int out_size, void* d_ws, size_t ws_size,
                              hipStream_t stream) {
    const float* feature = (const float*)d_in[0];
    const float* Wt      = (const float*)d_in[1];
    const float* Wd      = (const float*)d_in[2];
    const float* mem     = (const float*)d_in[3];
    const int*   cat     = (const int*)d_in[4];

    // ws layout: P2 (25.2 MB, aliases P's 6.3 MB — safe: P dead before fused writes P2,
    // stream-ordered) | gB 1.57 MB @50331648 | ssqp 128 KB
    float* P2 = (float*)d_ws;
    float* P  = (float*)d_ws;
    unsigned short* gB = (unsigned short*)((char*)d_ws + 50331648);
    float* ssqp = (float*)((char*)d_ws + 50331648 + 1572864);
    float* out = (float*)d_out;

    gproj2<<<256, 256, 0, stream>>>(Wt, Wd, mem, cat, P);
    split_g3<<<192, 256, 0, stream>>>(P, gB);
    fused_mfma6<<<512, 256, 0, stream>>>(feature, gB, P2, ssqp);
    ep_kernel<<<256, 256, 0, stream>>>(P2, ssqp, out);
}